// Round 12
// baseline (888.012 us; speedup 1.0000x reference)
//
#include <hip/hip_runtime.h>

typedef __attribute__((ext_vector_type(8))) short bf16x8;
typedef __attribute__((ext_vector_type(4))) short bf16x4;
typedef __attribute__((ext_vector_type(4))) float f32x4;

#define BATCH 2
#define CH    512
#define NPIX  4096

__device__ __forceinline__ unsigned short f2b(float f) {
    unsigned int u; __builtin_memcpy(&u, &f, 4);
    u = u + 0x7FFFu + ((u >> 16) & 1u);   // RNE
    return (unsigned short)(u >> 16);
}

// ---------------------------------------------------------------- fp32 -> bf16 weight convert
__global__ __launch_bounds__(256) void convert_kernel(
    const float* __restrict__ qkv_w, const float* __restrict__ proj_w,
    unsigned short* __restrict__ wbf)
{
    int i = blockIdx.x * 256 + threadIdx.x;            // grid covers 1048576
    float v = (i < 786432) ? qkv_w[i] : proj_w[i - 786432];
    wbf[i] = f2b(v);
}

// ---------------------------------------------------------------- GN stats
__global__ __launch_bounds__(256) void stats_kernel(
    const float* __restrict__ x, float* __restrict__ stats)
{
    int bg = blockIdx.x;           // 64 blocks: b*32+g
    int b = bg >> 5, g = bg & 31;
    const float* xp = x + ((size_t)b * CH + (size_t)g * 16) * NPIX;
    float s = 0.f, ss = 0.f;
    for (int i = threadIdx.x; i < 16 * NPIX; i += 256) {
        float v = xp[i]; s += v; ss += v * v;
    }
    for (int off = 32; off; off >>= 1) {
        s  += __shfl_down(s,  off, 64);
        ss += __shfl_down(ss, off, 64);
    }
    __shared__ float red[2][4];
    int wv = threadIdx.x >> 6;
    if ((threadIdx.x & 63) == 0) { red[0][wv] = s; red[1][wv] = ss; }
    __syncthreads();
    if (threadIdx.x == 0) {
        s  = red[0][0] + red[0][1] + red[0][2] + red[0][3];
        ss = red[1][0] + red[1][1] + red[1][2] + red[1][3];
        const float inv = 1.f / (16 * NPIX);
        float mean = s * inv;
        float var  = ss * inv - mean * mean;
        stats[bg * 2 + 0] = mean;
        stats[bg * 2 + 1] = rsqrtf(var + 1e-6f);
    }
}

// ---------------------------------------------------------------- K/V GEMM (unchanged from R11)
__global__ __launch_bounds__(256) void kv_kernel(
    const float* __restrict__ x,
    const unsigned short* __restrict__ wbf,
    const float* __restrict__ bias,
    const float* __restrict__ gamma,
    const float* __restrict__ beta,
    const float* __restrict__ stats,
    unsigned short* __restrict__ K,          // [b][n][c]
    unsigned short* __restrict__ V)          // [b][c][n]
{
    __shared__ unsigned short hn[32][520];
    int b  = blockIdx.y;
    int m0 = blockIdx.x * 32;
    int tid = threadIdx.x;
    {
        const float* xb = x + (size_t)b * CH * NPIX;
        const float* st = stats + b * 64;
        int p = tid & 31, cg = tid >> 5;
        for (int c0 = 0; c0 < CH; c0 += 8) {
            int c = c0 + cg;
            float mean = st[(c >> 4) * 2 + 0];
            float rstd = st[(c >> 4) * 2 + 1];
            float ga = gamma[c] * rstd;
            float be = beta[c] - mean * ga;
            hn[p][c] = f2b(xb[(size_t)c * NPIX + m0 + p] * ga + be);
        }
    }
    __syncthreads();

    int wv = tid >> 6, lane = tid & 63;
    int ln = lane & 15, quad = lane >> 4;
    #pragma unroll
    for (int nt = 0; nt < 16; nt++) {
        int o = nt * 64 + wv * 16 + ln;
        const unsigned short* bp = wbf + (size_t)(512 + o) * CH + quad * 8;
        bf16x8 wf[16];
        #pragma unroll
        for (int k = 0; k < 16; k++) wf[k] = *(const bf16x8*)(bp + k * 32);
        float bi = bias[512 + o];
        #pragma unroll
        for (int qt = 0; qt < 2; qt++) {
            f32x4 acc = {0.f, 0.f, 0.f, 0.f};
            #pragma unroll
            for (int k = 0; k < 16; k++) {
                bf16x8 a = *(const bf16x8*)(&hn[qt * 16 + ln][quad * 8 + k * 32]);
                acc = __builtin_amdgcn_mfma_f32_16x16x32_bf16(a, wf[k], acc, 0, 0, 0);
            }
            int m = m0 + qt * 16 + quad * 4;
            if (o < 512) {
                #pragma unroll
                for (int r = 0; r < 4; r++)
                    K[((size_t)b * NPIX + m + r) * CH + o] = f2b(acc[r] + bi);
            } else {
                bf16x4 pk;
                #pragma unroll
                for (int r = 0; r < 4; r++) pk[r] = f2b(acc[r] + bi);
                *(bf16x4*)(V + ((size_t)b * CH + o - 512) * NPIX + m) = pk;
            }
        }
    }
}

// ---------------------------------------------------------------- barrier-free flash attention + proj
// Block = 256 thr = 4 waves; 16 queries/block; wave w = key-quarter [w*1024,+1024).
// S^T = K*Q^T per wave (softmax state per-lane scalar); P via wave-private LDS
// (lgkmcnt-only wait, NO barriers in key loop); in-block merge of 4 quarters; fused proj.
__global__ __launch_bounds__(256, 2) void attnproj_kernel(
    const float* __restrict__ x,
    const unsigned short* __restrict__ qw,
    const float* __restrict__ qb,
    const float* __restrict__ gamma,
    const float* __restrict__ beta,
    const float* __restrict__ stats,
    const unsigned short* __restrict__ Kg,
    const unsigned short* __restrict__ Vg,
    const unsigned short* __restrict__ pw,
    const float* __restrict__ pb,
    float* __restrict__ out)
{
    // pool phases: [hn 16x520 | qls 16x520] -> [P 4x(16x80) | qls] -> [Osum 16x516 f32] -> [aobf 16x520]
    __shared__ char pool[34048];
    __shared__ float mls[2][4][16];
    __shared__ float alds[4][16];
    __shared__ float fls[4][16];
    __shared__ float linvb[16];

    unsigned short (*hn)[520]   = (unsigned short(*)[520])pool;
    unsigned short (*qls)[520]  = (unsigned short(*)[520])(pool + 17408);
    float (*Osum)[516]          = (float(*)[516])pool;
    unsigned short (*aobf)[520] = (unsigned short(*)[520])pool;

    int b  = blockIdx.y;
    int q0 = blockIdx.x * 16;
    int tid = threadIdx.x;
    int w = tid >> 6, lane = tid & 63, ln = lane & 15, quad = lane >> 4;
    const float* xb = x + (size_t)b * CH * NPIX;
    const unsigned short* K = Kg + (size_t)b * NPIX * CH;
    const unsigned short* V = Vg + (size_t)b * CH * NPIX;

    {   // stage hn[16][512]
        const float* st = stats + b * 64;
        int p = tid & 15, cg = tid >> 4;
        for (int c0 = 0; c0 < CH; c0 += 16) {
            int c = c0 + cg;
            float mean = st[(c >> 4) * 2 + 0];
            float rstd = st[(c >> 4) * 2 + 1];
            float ga = gamma[c] * rstd;
            float be = beta[c] - mean * ga;
            hn[p][c] = f2b(xb[(size_t)c * NPIX + q0 + p] * ga + be);
        }
    }
    __syncthreads();

    // ---- Q phase: q[16][512]; wave w computes channels [w*128,+128)
    const float scale = 0.04419417382415922f;  // 512^-0.5
    #pragma unroll
    for (int nt2 = 0; nt2 < 8; nt2++) {
        int o = w * 128 + nt2 * 16 + ln;
        const unsigned short* bp = qw + (size_t)o * CH + quad * 8;
        f32x4 acc = {0.f, 0.f, 0.f, 0.f};
        #pragma unroll
        for (int kt = 0; kt < 16; kt++) {
            bf16x8 a  = *(const bf16x8*)(&hn[ln][quad * 8 + kt * 32]);
            bf16x8 wf = *(const bf16x8*)(bp + kt * 32);
            acc = __builtin_amdgcn_mfma_f32_16x16x32_bf16(a, wf, acc, 0, 0, 0);
        }
        float bi = qb[o];
        #pragma unroll
        for (int r = 0; r < 4; r++)
            qls[quad * 4 + r][o] = f2b((acc[r] + bi) * scale);
    }
    __syncthreads();   // qls ready; hn region becomes P

    // q fragments in registers (B-operand: n=query=ln)
    bf16x8 qf[16];
    #pragma unroll
    for (int kt = 0; kt < 16; kt++)
        qf[kt] = *(const bf16x8*)(&qls[ln][quad * 8 + kt * 32]);

    unsigned short* Pw = (unsigned short*)pool + w * 1280;   // [16][80] bf16, wave-private

    f32x4 O32[32];
    #pragma unroll
    for (int nt = 0; nt < 32; nt++) O32[nt] = (f32x4){0.f, 0.f, 0.f, 0.f};
    float m = -1e30f, l = 0.f;
    int key0 = w * 1024;

    // ---- barrier-free flash over 64-key chunks
    for (int ck = 0; ck < 16; ck++) {
        int kpos = key0 + ck * 64;
        // S^T: D[key=quad*4+r][query=ln]; A=K-frag (m=key), B=q-frag (n=query)
        f32x4 S[4];
        #pragma unroll
        for (int g = 0; g < 4; g++) {
            const unsigned short* kp = K + (size_t)(kpos + g * 16 + ln) * CH + quad * 8;
            f32x4 s = {0.f, 0.f, 0.f, 0.f};
            #pragma unroll
            for (int kt = 0; kt < 16; kt++) {
                bf16x8 kf = *(const bf16x8*)(kp + kt * 32);
                s = __builtin_amdgcn_mfma_f32_16x16x32_bf16(kf, qf[kt], s, 0, 0, 0);
            }
            S[g] = s;
        }
        // per-lane softmax state for query ln
        float mx = m;
        #pragma unroll
        for (int g = 0; g < 4; g++)
            #pragma unroll
            for (int r = 0; r < 4; r++) mx = fmaxf(mx, S[g][r]);
        mx = fmaxf(mx, __shfl_xor(mx, 16, 64));
        mx = fmaxf(mx, __shfl_xor(mx, 32, 64));
        float alpha = __expf(m - mx);
        float sum = 0.f;
        #pragma unroll
        for (int g = 0; g < 4; g++) {
            bf16x4 pk;
            #pragma unroll
            for (int r = 0; r < 4; r++) {
                float e = __expf(S[g][r] - mx);
                sum += e; pk[r] = (short)f2b(e);
            }
            *(bf16x4*)(Pw + ln * 80 + g * 16 + quad * 4) = pk;   // P[q=ln][k]
        }
        sum += __shfl_xor(sum, 16, 64);
        sum += __shfl_xor(sum, 32, 64);
        l = l * alpha + sum; m = mx;
        if (quad == 0) alds[w][ln] = alpha;
        __builtin_amdgcn_s_waitcnt(0xC07F);   // lgkmcnt(0) only — wave-private LDS RAW
        f32x4 af = *(const f32x4*)&alds[w][quad * 4];
        #pragma unroll
        for (int nt = 0; nt < 32; nt++) {
            #pragma unroll
            for (int r = 0; r < 4; r++) O32[nt][r] *= af[r];
        }
        // PV: D[q=quad*4+r][c=nt*16+ln]; A=P[q][k], B=V[c][k]
        #pragma unroll
        for (int c2 = 0; c2 < 2; c2++) {
            bf16x8 pf = *(const bf16x8*)(Pw + ln * 80 + c2 * 32 + quad * 8);
            const unsigned short* vpb = V + (size_t)ln * NPIX + kpos + c2 * 32 + quad * 8;
            #pragma unroll
            for (int nt = 0; nt < 32; nt++) {
                bf16x8 vf = *(const bf16x8*)(vpb + (size_t)nt * 16 * NPIX);
                O32[nt] = __builtin_amdgcn_mfma_f32_16x16x32_bf16(pf, vf, O32[nt], 0, 0, 0);
            }
        }
    }

    // ---- merge 4 key-quarters
    if (quad == 0) { mls[0][w][ln] = m; mls[1][w][ln] = l; }
    __syncthreads();
    if (tid < 16) {
        float ms = fmaxf(fmaxf(mls[0][0][tid], mls[0][1][tid]),
                         fmaxf(mls[0][2][tid], mls[0][3][tid]));
        float ls = 0.f;
        #pragma unroll
        for (int w2 = 0; w2 < 4; w2++) {
            float f = __expf(mls[0][w2][tid] - ms);
            fls[w2][tid] = f;
            ls += mls[1][w2][tid] * f;
        }
        linvb[tid] = 1.f / ls;
    }
    __syncthreads();
    {
        f32x4 ff = *(const f32x4*)&fls[w][quad * 4];
        #pragma unroll
        for (int nt = 0; nt < 32; nt++) {
            #pragma unroll
            for (int r = 0; r < 4; r++) O32[nt][r] *= ff[r];
        }
    }
    for (int w2 = 0; w2 < 4; w2++) {      // Osum overlays P+qls (both dead)
        if (w == w2) {
            #pragma unroll
            for (int nt = 0; nt < 32; nt++) {
                #pragma unroll
                for (int r = 0; r < 4; r++) {
                    float* dst = &Osum[quad * 4 + r][nt * 16 + ln];
                    if (w2 == 0) *dst = O32[nt][r]; else *dst += O32[nt][r];
                }
            }
        }
        __syncthreads();
    }

    // ---- normalize -> aobf (two-step through registers; aobf overlays Osum)
    float tmp[32];
    {
        int q = tid >> 4, cbase = (tid & 15) * 32;
        float li = linvb[q];
        #pragma unroll
        for (int i = 0; i < 32; i++) tmp[i] = Osum[q][cbase + i] * li;
    }
    __syncthreads();
    {
        int q = tid >> 4, cbase = (tid & 15) * 32;
        #pragma unroll
        for (int i = 0; i < 32; i++) aobf[q][cbase + i] = f2b(tmp[i]);
    }
    __syncthreads();

    // ---- proj + bias + residual; wave w -> out channels [w*128,+128)
    #pragma unroll
    for (int nt2 = 0; nt2 < 8; nt2++) {
        int o = w * 128 + nt2 * 16 + ln;
        const unsigned short* bp = pw + (size_t)o * CH + quad * 8;
        f32x4 acc = {0.f, 0.f, 0.f, 0.f};
        #pragma unroll
        for (int kt = 0; kt < 16; kt++) {
            bf16x8 a  = *(const bf16x8*)(&aobf[ln][quad * 8 + kt * 32]);
            bf16x8 wf = *(const bf16x8*)(bp + kt * 32);
            acc = __builtin_amdgcn_mfma_f32_16x16x32_bf16(a, wf, acc, 0, 0, 0);
        }
        float bi = pb[o];
        size_t base = ((size_t)b * CH + o) * NPIX + q0 + quad * 4;
        f32x4 xin = *(const f32x4*)(x + base);
        f32x4 o4;
        #pragma unroll
        for (int r = 0; r < 4; r++) o4[r] = xin[r] + acc[r] + bi;
        *(f32x4*)(out + base) = o4;
    }
}

// ----------------------------------------------------------------
extern "C" void kernel_launch(void* const* d_in, const int* in_sizes, int n_in,
                              void* d_out, int out_size, void* d_ws, size_t ws_size,
                              hipStream_t stream)
{
    const float* x      = (const float*)d_in[0];
    const float* gn_g   = (const float*)d_in[1];
    const float* gn_b   = (const float*)d_in[2];
    const float* qkv_w  = (const float*)d_in[3];
    const float* qkv_b  = (const float*)d_in[4];
    const float* proj_w = (const float*)d_in[5];
    const float* proj_b = (const float*)d_in[6];
    float* out = (float*)d_out;

    // Workspace: K 8MB | V 8MB | weights-bf16 2MB | stats 512B
    unsigned short* ws  = (unsigned short*)d_ws;
    unsigned short* Kb  = ws;                         // [2][4096][512] bf16
    unsigned short* Vb  = ws + 4u * 1024 * 1024;      // [2][512][4096] bf16
    unsigned short* wbf = ws + 8u * 1024 * 1024;      // qkv_w | proj_w, bf16
    unsigned short* wq  = wbf;
    unsigned short* wp  = wbf + 786432;
    float* stats = (float*)(ws + 9u * 1024 * 1024 + 256u * 1024);

    convert_kernel<<<dim3(1048576 / 256), 256, 0, stream>>>(qkv_w, proj_w, wbf);
    stats_kernel  <<<dim3(64), 256, 0, stream>>>(x, stats);
    kv_kernel     <<<dim3(NPIX / 32, BATCH), 256, 0, stream>>>(
        x, wbf, qkv_b, gn_g, gn_b, stats, Kb, Vb);
    attnproj_kernel<<<dim3(NPIX / 16, BATCH), 256, 0, stream>>>(
        x, wq, qkv_b, gn_g, gn_b, stats, Kb, Vb, wp, proj_b, out);
}